// Round 1
// baseline (488.089 us; speedup 1.0000x reference)
//
#include <hip/hip_runtime.h>

typedef int v4i __attribute__((ext_vector_type(4)));

#define G_AS1 const __attribute__((address_space(1))) unsigned int
#define L_AS3 __attribute__((address_space(3))) unsigned int

// ---------------------------------------------------------------------------
// Per-row symmetric int8 fake-quant: scale = max(|row|)/127 (clamped 1e-8),
// q = clip(rintf(v/scale), -127, 127). One block per row, ncols == 4096.
// IEEE division + rintf (round-half-even) to bit-match jnp.round(v/scale).
// ---------------------------------------------------------------------------
__global__ __launch_bounds__(256) void quant_rows_kernel(
    const float* __restrict__ in, signed char* __restrict__ q,
    float* __restrict__ scale, int ncols)
{
    const int row = blockIdx.x;
    const int tid = threadIdx.x;
    const float4* inr = (const float4*)(in + (size_t)row * ncols);
    int* qr = (int*)(q + (size_t)row * ncols);

    float4 v[4];
    float amax = 0.0f;
#pragma unroll
    for (int i = 0; i < 4; ++i) {
        float4 t = inr[tid + i * 256];
        v[i] = t;
        amax = fmaxf(amax, fmaxf(fmaxf(fabsf(t.x), fabsf(t.y)),
                                 fmaxf(fabsf(t.z), fabsf(t.w))));
    }
    // wave64 butterfly reduce
#pragma unroll
    for (int off = 32; off > 0; off >>= 1)
        amax = fmaxf(amax, __shfl_xor(amax, off));

    __shared__ float s_am[4];
    const int lane = tid & 63, wid = tid >> 6;
    if (lane == 0) s_am[wid] = amax;
    __syncthreads();
    amax = fmaxf(fmaxf(s_am[0], s_am[1]), fmaxf(s_am[2], s_am[3]));

    const float sc = fmaxf(amax / 127.0f, 1e-8f);  // IEEE div, matches ref
    if (tid == 0) scale[row] = sc;

#pragma unroll
    for (int i = 0; i < 4; ++i) {
        float4 t = v[i];
        int b0 = (int)fminf(fmaxf(rintf(t.x / sc), -127.0f), 127.0f);
        int b1 = (int)fminf(fmaxf(rintf(t.y / sc), -127.0f), 127.0f);
        int b2 = (int)fminf(fmaxf(rintf(t.z / sc), -127.0f), 127.0f);
        int b3 = (int)fminf(fmaxf(rintf(t.w / sc), -127.0f), 127.0f);
        qr[tid + i * 256] = (b0 & 255) | ((b1 & 255) << 8) |
                            ((b2 & 255) << 16) | (b3 << 24);
    }
}

// ---------------------------------------------------------------------------
// int8 GEMM: C[m,n] = float(sum_k A[m,k]*B[n,k]) * sA[m]*sB[n] + bias[n]
// A: [M][K] int8 row-major (q_x), B: [N][K] int8 row-major (q_w, i.e. B^T).
// 128x128 tile, BK=64, 256 threads = 4 waves (2x2), 4x4 16x16x64 frags/wave.
// m97 structure: global_load_lds width-16 staging, linear LDS, 2 barriers/K.
// ---------------------------------------------------------------------------
__global__ __launch_bounds__(256) void gemm_i8_kernel(
    const signed char* __restrict__ A, const signed char* __restrict__ B,
    const float* __restrict__ sA, const float* __restrict__ sB,
    const float* __restrict__ bias, float* __restrict__ C,
    int M, int N, int K)
{
    __shared__ __attribute__((aligned(16))) signed char As[128 * 64];
    __shared__ __attribute__((aligned(16))) signed char Bs[128 * 64];

    const int tid = threadIdx.x;
    const int lane = tid & 63, wid = tid >> 6;
    const int wm = wid >> 1, wn = wid & 1;

    // XCD-aware bijective blockIdx swizzle (m204 form)
    const int nwg = gridDim.x;
    const int xcd = blockIdx.x & 7, loc = blockIdx.x >> 3;
    const int qq = nwg >> 3, rr = nwg & 7;
    const int wg = (xcd < rr ? xcd * (qq + 1) : rr * (qq + 1) + (xcd - rr) * qq) + loc;

    const int nbn = N >> 7;            // N/128
    const int m0 = (wg / nbn) << 7;
    const int n0 = (wg % nbn) << 7;

    // staging: each thread owns 16 contiguous bytes; 2 instrs per tile half
    const int rowT = tid >> 2;          // 0..63
    const int chT  = (tid & 3) << 4;    // 0,16,32,48
    const signed char* gA = A + (size_t)(m0 + rowT) * K + chT;
    const signed char* gB = B + (size_t)(n0 + rowT) * K + chT;
    const size_t rstep = (size_t)64 * K;

    L_AS3* ldsA0 = (L_AS3*)(As + (wid << 10));
    L_AS3* ldsA1 = (L_AS3*)(As + 4096 + (wid << 10));
    L_AS3* ldsB0 = (L_AS3*)(Bs + (wid << 10));
    L_AS3* ldsB1 = (L_AS3*)(Bs + 4096 + (wid << 10));

    // fragment read addresses: row = (l&15), k-chunk = (l>>4)*16 bytes
    const int l15 = lane & 15;
    const int kq  = (lane >> 4) << 4;
    const signed char* pA = As + ((((wm << 6) + l15) << 6) + kq);
    const signed char* pB = Bs + ((((wn << 6) + l15) << 6) + kq);

    v4i acc[4][4];
    const v4i vzero = {0, 0, 0, 0};
#pragma unroll
    for (int i = 0; i < 4; ++i)
#pragma unroll
        for (int j = 0; j < 4; ++j)
            acc[i][j] = vzero;

    for (int kt = 0; kt < K; kt += 64) {
        __builtin_amdgcn_global_load_lds((G_AS1*)gA,           ldsA0, 16, 0, 0);
        __builtin_amdgcn_global_load_lds((G_AS1*)(gA + rstep), ldsA1, 16, 0, 0);
        __builtin_amdgcn_global_load_lds((G_AS1*)gB,           ldsB0, 16, 0, 0);
        __builtin_amdgcn_global_load_lds((G_AS1*)(gB + rstep), ldsB1, 16, 0, 0);
        gA += 64; gB += 64;
        __syncthreads();

        v4i a[4], b[4];
#pragma unroll
        for (int f = 0; f < 4; ++f) {
            a[f] = *(const v4i*)(pA + (f << 10));
            b[f] = *(const v4i*)(pB + (f << 10));
        }
#pragma unroll
        for (int fm = 0; fm < 4; ++fm)
#pragma unroll
            for (int fn = 0; fn < 4; ++fn)
                acc[fm][fn] = __builtin_amdgcn_mfma_i32_16x16x64_i8(
                    a[fm], b[fn], acc[fm][fn], 0, 0, 0);
        __syncthreads();
    }

    // epilogue: C/D layout col=lane&15, row=(lane>>4)*4+reg (dtype-independent)
    const int r4 = (lane >> 4) << 2;
#pragma unroll
    for (int fn = 0; fn < 4; ++fn) {
        const int col = n0 + (wn << 6) + (fn << 4) + l15;
        const float sb = sB[col];
        const float bv = bias[col];
#pragma unroll
        for (int fm = 0; fm < 4; ++fm) {
            const int rowb = m0 + (wm << 6) + (fm << 4) + r4;
#pragma unroll
            for (int r = 0; r < 4; ++r) {
                const int row = rowb + r;
                C[(size_t)row * N + col] =
                    (float)acc[fm][fn][r] * (sA[row] * sb) + bv;
            }
        }
    }
}

// ---------------------------------------------------------------------------
extern "C" void kernel_launch(void* const* d_in, const int* in_sizes, int n_in,
                              void* d_out, int out_size, void* d_ws, size_t ws_size,
                              hipStream_t stream) {
    const float* x    = (const float*)d_in[0];   // [M][K] fp32
    const float* w    = (const float*)d_in[1];   // [N][K] fp32
    const float* bias = (const float*)d_in[2];   // [N]
    float* out = (float*)d_out;

    const int N = in_sizes[2];            // 4096
    const int K = in_sizes[1] / N;        // 4096
    const int M = in_sizes[0] / K;        // 8192

    signed char* qx = (signed char*)d_ws;
    signed char* qw = qx + (size_t)M * K;
    float* sx = (float*)(qw + (size_t)N * K);
    float* sw = sx + M;

    quant_rows_kernel<<<M, 256, 0, stream>>>(x, qx, sx, K);
    quant_rows_kernel<<<N, 256, 0, stream>>>(w, qw, sw, K);

    dim3 grid((M / 128) * (N / 128));     // 2048 blocks
    gemm_i8_kernel<<<grid, 256, 0, stream>>>(qx, qw, sx, sw, bias, out, M, N, K);
}